// Round 5
// baseline (1522.491 us; speedup 1.0000x reference)
//
#include <hip/hip_runtime.h>
#include <math.h>

typedef unsigned short u16;
typedef unsigned int u32;

using bf16x8 = __attribute__((ext_vector_type(8))) __bf16;
using f32x4  = __attribute__((ext_vector_type(4))) float;

#define SEQ 3072
#define HID 1280
#define NHEADS 16
#define HDIM 80
#define INTER 4608

#define LOG2E 1.44269504088896f
#define M2C   11.5415603f   /* 8 * log2(e) */

__device__ __forceinline__ u16 f2bf(float f) {
    __bf16 h = (__bf16)f;               // HW v_cvt, RNE
    return __builtin_bit_cast(u16, h);
}

__device__ __forceinline__ void gld16(const void* g, void* l) {
    __builtin_amdgcn_global_load_lds((const __attribute__((address_space(1))) void*)g,
                                     (__attribute__((address_space(3))) void*)l,
                                     16, 0, 0);
}

// swizzled fragment read: row-major tiles of 8 u16 chunks, chunk c at slot c^(row&7)
__device__ __forceinline__ bf16x8 frag8(const u16* base, int row, int ks, int quad) {
    int c = ks * 4 + quad;
    return *(const bf16x8*)&base[(row * 8 + (c ^ (row & 7))) * 8];
}

// ---------------- transpose + bf16 pack:  W (L,K,N) f32  ->  Wt (L,N,K) bf16
__global__ __launch_bounds__(256) void transpose_pack(const float* __restrict__ src,
                                                      u16* __restrict__ dst, int K, int N) {
    __shared__ float tile[32][33];
    int l = blockIdx.z;
    const float* s = src + (size_t)l * K * N;
    u16* d = dst + (size_t)l * N * K;
    int n0 = blockIdx.x * 32, k0 = blockIdx.y * 32;
    int tx = threadIdx.x & 31, ty = threadIdx.x >> 5;
#pragma unroll
    for (int i = 0; i < 4; i++) {
        int k = ty + i * 8;
        tile[k][tx] = s[(size_t)(k0 + k) * N + n0 + tx];
    }
    __syncthreads();
#pragma unroll
    for (int i = 0; i < 4; i++) {
        int n = ty + i * 8;
        d[(size_t)(n0 + n) * K + k0 + tx] = f2bf(tile[tx][n]);
    }
}

// transpose+pack gate/up into a single interleaved buffer (L, 2N, K):
// real col g, which in {0:gate, 1:up} -> row n2 = ((g>>4)<<5) | (g&15) | (which<<4)
__global__ __launch_bounds__(256) void transpose_pack_gu(const float* __restrict__ src,
                                                         u16* __restrict__ dst, int K, int N,
                                                         int which) {
    __shared__ float tile[32][33];
    int l = blockIdx.z;
    const float* s = src + (size_t)l * K * N;
    u16* d = dst + (size_t)l * (2 * N) * K;
    int n0 = blockIdx.x * 32, k0 = blockIdx.y * 32;
    int tx = threadIdx.x & 31, ty = threadIdx.x >> 5;
#pragma unroll
    for (int i = 0; i < 4; i++) {
        int k = ty + i * 8;
        tile[k][tx] = s[(size_t)(k0 + k) * N + n0 + tx];
    }
    __syncthreads();
#pragma unroll
    for (int i = 0; i < 4; i++) {
        int n = ty + i * 8;
        int g = n0 + n;
        int n2 = ((g >> 4) << 5) | (g & 15) | (which << 4);
        d[(size_t)n2 * K + k0 + tx] = f2bf(tile[tx][n]);
    }
}

// ---------------- layernorm f32 -> bf16 (one row per block)
__global__ __launch_bounds__(256) void ln_kernel(const float* __restrict__ x,
                                                 const float* __restrict__ w,
                                                 const float* __restrict__ b,
                                                 u16* __restrict__ out) {
    int row = blockIdx.x;
    const float* xr = x + (size_t)row * HID;
    float v[5]; float s = 0.f, s2 = 0.f;
#pragma unroll
    for (int i = 0; i < 5; i++) { float t = xr[threadIdx.x + i * 256]; v[i] = t; s += t; s2 += t * t; }
#pragma unroll
    for (int off = 32; off > 0; off >>= 1) { s += __shfl_down(s, off); s2 += __shfl_down(s2, off); }
    __shared__ float red[8];
    int wv = threadIdx.x >> 6;
    if ((threadIdx.x & 63) == 0) { red[wv] = s; red[wv + 4] = s2; }
    __syncthreads();
    s  = red[0] + red[1] + red[2] + red[3];
    s2 = red[4] + red[5] + red[6] + red[7];
    float mu  = s * (1.f / HID);
    float var = s2 * (1.f / HID) - mu * mu;
    float rstd = rsqrtf(var + 1e-6f);
#pragma unroll
    for (int i = 0; i < 5; i++) {
        int col = threadIdx.x + i * 256;
        out[(size_t)row * HID + col] = f2bf((v[i] - mu) * rstd * w[col] + b[col]);
    }
}

// ---------------- qkv pack: fp32 qkv (S,3,16,80) -> rotary + bf16 attention layouts
__global__ __launch_bounds__(256) void qkv_pack(const float* __restrict__ qkv,
                                                const float* __restrict__ rot,
                                                u16* __restrict__ Qp, u16* __restrict__ Kp,
                                                u16* __restrict__ Vt) {
    const float QSC = 0.111803398874989485f * LOG2E;
    int s0 = blockIdx.x * 64, h = blockIdx.y;
    int tid = threadIdx.x;
    __shared__ u16 vlds[80 * 66];
    for (int idx = tid; idx < 64 * 40; idx += 256) {
        int r = idx / 40, d = idx - r * 40;
        const float* base = qkv + (size_t)(s0 + r) * 3840 + h * 80;
        float sn, cs;
        __sincosf(rot[(size_t)(s0 + r) * 40 + d], &sn, &cs);
        float q1 = base[d], q2 = base[d + 40];
        float k1 = base[1280 + d], k2 = base[1280 + d + 40];
        size_t ro = ((size_t)h * SEQ + s0 + r) * 128;
        Qp[ro + d]      = f2bf((q1 * cs - q2 * sn) * QSC);
        Qp[ro + d + 40] = f2bf((q2 * cs + q1 * sn) * QSC);
        Kp[ro + d]      = f2bf(k1 * cs - k2 * sn);
        Kp[ro + d + 40] = f2bf(k2 * cs + k1 * sn);
    }
    for (int idx = tid; idx < 64 * 48; idx += 256) {
        int r = idx / 48, d = 80 + (idx - r * 48);
        size_t ro = ((size_t)h * SEQ + s0 + r) * 128;
        Qp[ro + d] = 0; Kp[ro + d] = 0;
    }
    for (int idx = tid; idx < 64 * 80; idx += 256) {
        int r = idx / 80, d = idx - r * 80;
        vlds[d * 66 + r] = f2bf(qkv[(size_t)(s0 + r) * 3840 + 2560 + h * 80 + d]);
    }
    __syncthreads();
    for (int idx = tid; idx < 80 * 64; idx += 256) {
        int d = idx >> 6, ky = idx & 63;
        Vt[((size_t)h * 80 + d) * SEQ + s0 + ky] = vlds[d * 66 + ky];
    }
}

// ---------------- gemm256: 192x256 tile, 8 waves (2M x 4N), BK=64, per-wave 96x64.
// A dbuf (2x24KB) + B tbuf (3x32KB) = 147456 B LDS.  ONE barrier per K-tile:
// skew bounded <1 tile; A buf reused at distance 2, B at 3 -> no cross-wave race.
// vmcnt(4) at boundary leaves B(t+2) in flight; compiler fence between the
// A-stage and B-stage clusters keeps the vm issue order the count relies on.
// EPI 0: f32+bias (qkv). EPI 2: dual interleaved gate/up, silu fuse, bf16 out.
template<int EPI>
__global__ __launch_bounds__(512, 2) void gemm256(const u16* __restrict__ A,
                                                  const u16* __restrict__ B,
                                                  const float* __restrict__ bias0,
                                                  const float* __restrict__ bias1,
                                                  float* __restrict__ outf,
                                                  u16* __restrict__ outh,
                                                  int N, int K) {
    __shared__ u16 sbuf[73728];          // A 2x12288 u16, B 3x16384 u16
    int tid = threadIdx.x, lane = tid & 63, wave = tid >> 6;
    int quad = lane >> 4, r15 = lane & 15;
    int wm = wave >> 2, wn = wave & 3;   // 2M x 4N; per-wave out 96x64

    // bijective XCD swizzle (m204)
    int nwg = gridDim.x;
    int q8 = nwg >> 3, r8 = nwg & 7;
    int xcd = blockIdx.x & 7, j = blockIdx.x >> 3;
    int wg = (xcd < r8 ? xcd * (q8 + 1) : r8 * (q8 + 1) + (xcd - r8) * q8) + j;
    int bx = wg >> 4, by = wg & 15;      // M = 3072 -> 16 row tiles of 192
    int mBase = by * 192, nBase = bx * 256;

    int rs = tid >> 3, cs = tid & 7;
    int c0 = cs ^ (rs & 7);
    const u16* gA = A + (size_t)(mBase + rs) * K + c0 * 8;
    const u16* gB = B + (size_t)(nBase + rs) * K + c0 * 8;
    int nK = K >> 6;

    // hoisted swizzled LDS byte offsets (loop-invariant)
    int offA[2][6], offB[2][4];
#pragma unroll
    for (int ks = 0; ks < 2; ks++) {
#pragma unroll
        for (int mi = 0; mi < 6; mi++) {
            int row = wm * 96 + mi * 16 + r15, c = ks * 4 + quad;
            offA[ks][mi] = (row * 8 + (c ^ (row & 7))) * 8;
        }
#pragma unroll
        for (int ni = 0; ni < 4; ni++) {
            int row = wn * 64 + ni * 16 + r15, c = ks * 4 + quad;
            offB[ks][ni] = (row * 8 + (c ^ (row & 7))) * 8;
        }
    }

    f32x4 acc[6][4] = {};

    auto stageA = [&](int kt, int jl) {
        gld16(gA + (size_t)kt * 64 + (size_t)(jl * 64) * K,
              &sbuf[(kt & 1) * 12288 + jl * 4096 + wave * 512]);
    };
    auto stageB = [&](int kt, int jl) {
        gld16(gB + (size_t)kt * 64 + (size_t)(jl * 64) * K,
              &sbuf[24576 + (kt % 3) * 16384 + jl * 4096 + wave * 512]);
    };

    // prologue: A(0)+B(0) (oldest 7), fence, B(1) (newest 4)
#pragma unroll
    for (int jl = 0; jl < 3; jl++) stageA(0, jl);
#pragma unroll
    for (int jl = 0; jl < 4; jl++) stageB(0, jl);
    asm volatile("" ::: "memory");
#pragma unroll
    for (int jl = 0; jl < 4; jl++) stageB(1, jl);
    asm volatile("s_waitcnt vmcnt(4)" ::: "memory");
    __builtin_amdgcn_s_barrier();

    for (int kt = 0; kt < nK; kt++) {
        const u16* Ab = &sbuf[(kt & 1) * 12288];
        const u16* Bb = &sbuf[24576 + (kt % 3) * 16384];
        bool preA = (kt + 1 < nK), preB = (kt + 2 < nK);
        // ---- ks = 0
        {
            bf16x8 af[6], bf[4];
#pragma unroll
            for (int mi = 0; mi < 6; mi++) af[mi] = *(const bf16x8*)&Ab[offA[0][mi]];
#pragma unroll
            for (int ni = 0; ni < 4; ni++) bf[ni] = *(const bf16x8*)&Bb[offB[0][ni]];
            if (preA) { stageA(kt + 1, 0); stageA(kt + 1, 1); stageA(kt + 1, 2); }
            asm volatile("" ::: "memory");   // keep A-stages older than B-stages
            __builtin_amdgcn_s_setprio(1);
#pragma unroll
            for (int mi = 0; mi < 6; mi++)
#pragma unroll
                for (int ni = 0; ni < 4; ni++)
                    acc[mi][ni] = __builtin_amdgcn_mfma_f32_16x16x32_bf16(
                        af[mi], bf[ni], acc[mi][ni], 0, 0, 0);
            __builtin_amdgcn_s_setprio(0);
        }
        // ---- ks = 1
        {
            bf16x8 af[6], bf[4];
#pragma unroll
            for (int mi = 0; mi < 6; mi++) af[mi] = *(const bf16x8*)&Ab[offA[1][mi]];
#pragma unroll
            for (int ni = 0; ni < 4; ni++) bf[ni] = *(const bf16x8*)&Bb[offB[1][ni]];
            if (preB) { stageB(kt + 2, 0); stageB(kt + 2, 1); stageB(kt + 2, 2); stageB(kt + 2, 3); }
            __builtin_amdgcn_s_setprio(1);
#pragma unroll
            for (int mi = 0; mi < 6; mi++)
#pragma unroll
                for (int ni = 0; ni < 4; ni++)
                    acc[mi][ni] = __builtin_amdgcn_mfma_f32_16x16x32_bf16(
                        af[mi], bf[ni], acc[mi][ni], 0, 0, 0);
            __builtin_amdgcn_s_setprio(0);
        }
        // ---- tile boundary: single barrier per tile
        if (preB)      { asm volatile("s_waitcnt vmcnt(4)" ::: "memory"); }
        else if (preA) { asm volatile("s_waitcnt vmcnt(0)" ::: "memory"); }
        __builtin_amdgcn_s_barrier();
    }

    if constexpr (EPI == 0) {
#pragma unroll
        for (int ni = 0; ni < 4; ni++) {
            int col = nBase + wn * 64 + ni * 16 + r15;
            float bv = bias0[col];
#pragma unroll
            for (int a = 0; a < 6; a++)
#pragma unroll
                for (int jj = 0; jj < 4; jj++) {
                    int row = mBase + wm * 96 + a * 16 + quad * 4 + jj;
                    outf[(size_t)row * N + col] = acc[a][ni][jj] + bv;
                }
        }
    } else {
        // interleaved dual: even ni = gate frag, odd ni = up frag (same real cols)
#pragma unroll
        for (int pp = 0; pp < 2; pp++) {
            int col = (nBase >> 1) + wn * 32 + pp * 16 + r15;
            float gb = bias0[col], ub = bias1[col];
#pragma unroll
            for (int a = 0; a < 6; a++)
#pragma unroll
                for (int jj = 0; jj < 4; jj++) {
                    int row = mBase + wm * 96 + a * 16 + quad * 4 + jj;
                    float g = acc[a][2 * pp][jj] + gb;
                    float u = acc[a][2 * pp + 1][jj] + ub;
                    float sg = g / (1.f + __expf(-g));
                    outh[(size_t)row * INTER + col] = f2bf(sg * u);
                }
        }
    }
}

// ---------------- gemm8 (proj / down): 128x128 tile, 8 waves (2M x 4N), BK=64.
// A dbuf (2x16KB) + B tbuf (3x16KB) = 81920 B -> 2 blocks/CU. Same thinned
// 1-barrier schedule; vmcnt(2) leaves B(t+2) in flight. EPI1: bias+residual f32.
template<int EPI>
__global__ __launch_bounds__(512, 4) void gemm8(const u16* __restrict__ A,
                                                const u16* __restrict__ B,
                                                const float* __restrict__ bias0,
                                                const float* __restrict__ res,
                                                float* __restrict__ outf,
                                                int N, int K) {
    __shared__ u16 sbuf[40960];          // A 2x8192 u16, B 3x8192 u16
    int tid = threadIdx.x, lane = tid & 63, wave = tid >> 6;
    int quad = lane >> 4, r15 = lane & 15;
    int wm = wave >> 2, wn = wave & 3;   // per-wave out 64x32

    int nwg = gridDim.x;
    int q8 = nwg >> 3, r8 = nwg & 7;
    int xcd = blockIdx.x & 7, j = blockIdx.x >> 3;
    int wg = (xcd < r8 ? xcd * (q8 + 1) : r8 * (q8 + 1) + (xcd - r8) * q8) + j;
    int bx = wg / 24, by = wg % 24;      // M = 3072 -> 24 row tiles of 128
    int mBase = by * 128, nBase = bx * 128;

    int rs = tid >> 3, cs = tid & 7;
    int c0 = cs ^ (rs & 7);
    const u16* gA = A + (size_t)(mBase + rs) * K + c0 * 8;
    const u16* gB = B + (size_t)(nBase + rs) * K + c0 * 8;
    int nK = K >> 6;

    int offA[2][4], offB[2][2];
#pragma unroll
    for (int ks = 0; ks < 2; ks++) {
#pragma unroll
        for (int mi = 0; mi < 4; mi++) {
            int row = wm * 64 + mi * 16 + r15, c = ks * 4 + quad;
            offA[ks][mi] = (row * 8 + (c ^ (row & 7))) * 8;
        }
#pragma unroll
        for (int ni = 0; ni < 2; ni++) {
            int row = wn * 32 + ni * 16 + r15, c = ks * 4 + quad;
            offB[ks][ni] = (row * 8 + (c ^ (row & 7))) * 8;
        }
    }

    f32x4 acc[4][2] = {};

    auto stageA = [&](int kt, int jl) {
        gld16(gA + (size_t)kt * 64 + (size_t)(jl * 64) * K,
              &sbuf[(kt & 1) * 8192 + jl * 4096 + wave * 512]);
    };
    auto stageB = [&](int kt, int jl) {
        gld16(gB + (size_t)kt * 64 + (size_t)(jl * 64) * K,
              &sbuf[16384 + (kt % 3) * 8192 + jl * 4096 + wave * 512]);
    };

#pragma unroll
    for (int jl = 0; jl < 2; jl++) stageA(0, jl);
#pragma unroll
    for (int jl = 0; jl < 2; jl++) stageB(0, jl);
    asm volatile("" ::: "memory");
#pragma unroll
    for (int jl = 0; jl < 2; jl++) stageB(1, jl);
    asm volatile("s_waitcnt vmcnt(2)" ::: "memory");
    __builtin_amdgcn_s_barrier();

    for (int kt = 0; kt < nK; kt++) {
        const u16* Ab = &sbuf[(kt & 1) * 8192];
        const u16* Bb = &sbuf[16384 + (kt % 3) * 8192];
        bool preA = (kt + 1 < nK), preB = (kt + 2 < nK);
        // ks = 0
        {
            bf16x8 af[4], bf[2];
#pragma unroll
            for (int mi = 0; mi < 4; mi++) af[mi] = *(const bf16x8*)&Ab[offA[0][mi]];
#pragma unroll
            for (int ni = 0; ni < 2; ni++) bf[ni] = *(const bf16x8*)&Bb[offB[0][ni]];
            if (preA) { stageA(kt + 1, 0); stageA(kt + 1, 1); }
            asm volatile("" ::: "memory");
            __builtin_amdgcn_s_setprio(1);
#pragma unroll
            for (int mi = 0; mi < 4; mi++)
#pragma unroll
                for (int ni = 0; ni < 2; ni++)
                    acc[mi][ni] = __builtin_amdgcn_mfma_f32_16x16x32_bf16(
                        af[mi], bf[ni], acc[mi][ni], 0, 0, 0);
            __builtin_amdgcn_s_setprio(0);
        }
        // ks = 1
        {
            bf16x8 af[4], bf[2];
#pragma unroll
            for (int mi = 0; mi < 4; mi++) af[mi] = *(const bf16x8*)&Ab[offA[1][mi]];
#pragma unroll
            for (int ni = 0; ni < 2; ni++) bf[ni] = *(const bf16x8*)&Bb[offB[1][ni]];
            if (preB) { stageB(kt + 2, 0); stageB(kt + 2, 1); }
            __builtin_amdgcn_s_setprio(1);
#pragma unroll
            for (int mi = 0; mi < 4; mi++)
#pragma unroll
                for (int ni = 0; ni < 2; ni++)
                    acc[mi][ni] = __builtin_amdgcn_mfma_f32_16x16x32_bf16(
                        af[mi], bf[ni], acc[mi][ni], 0, 0, 0);
            __builtin_amdgcn_s_setprio(0);
        }
        if (preB)      { asm volatile("s_waitcnt vmcnt(2)" ::: "memory"); }
        else if (preA) { asm volatile("s_waitcnt vmcnt(0)" ::: "memory"); }
        __builtin_amdgcn_s_barrier();
    }

#pragma unroll
    for (int ni = 0; ni < 2; ni++) {
        int col = nBase + wn * 32 + ni * 16 + r15;
        float bv = bias0[col];
#pragma unroll
        for (int mi = 0; mi < 4; mi++)
#pragma unroll
            for (int jj = 0; jj < 4; jj++) {
                int row = mBase + wm * 64 + mi * 16 + quad * 4 + jj;
                float v = acc[mi][ni][jj] + bv;
                if constexpr (EPI == 1) v += res[(size_t)row * N + col];
                outf[(size_t)row * N + col] = v;
            }
    }
}

// ---------------- flash attention with sinks, QR query rows per block.
// Full layer (QR=128, nT>1): T14 async-stage — next tile's K/V loaded to regs
// before compute, written to LDS after the post-compute barrier.
template<int QR>
__global__ __launch_bounds__(256) void attn_kernel(const u16* __restrict__ Qp,
                                                   const u16* __restrict__ Kp,
                                                   const u16* __restrict__ Vt,
                                                   const float* __restrict__ s_aux,
                                                   u16* __restrict__ out) {
    constexpr int MH = QR / 64;
    __shared__ u16 q_lds[QR * 128];
    __shared__ u16 k_lds[8192];
    __shared__ u16 v_lds[5120];
    __shared__ u16 p_lds[QR * 72];

    int qt = blockIdx.x, h = blockIdx.y;
    int tid = threadIdx.x, lane = tid & 63, wave = tid >> 6;
    int quad = lane >> 4, r15 = lane & 15;

    const u16* Qh = Qp + (size_t)h * SEQ * 128;
    const u16* Kh = Kp + (size_t)h * SEQ * 128;
    const u16* Vh = Vt + (size_t)h * 80 * SEQ;

    {
        int q0 = qt * QR;
#pragma unroll
        for (int i = 0; i < QR / 16; i++) {
            int slot = i * 256 + tid;
            int row = slot >> 4, cc = slot & 15;
            int c = cc ^ (row & 7);
            gld16(Qh + (size_t)(q0 + row) * 128 + c * 8, &q_lds[(i * 256 + wave * 64) * 8]);
        }
    }
    __syncthreads();
    bf16x8 aq[MH][3];
#pragma unroll
    for (int mh = 0; mh < MH; mh++)
#pragma unroll
        for (int ks = 0; ks < 3; ks++) {
            int row = wave * (16 * MH) + mh * 16 + r15;
            int c = ks * 4 + quad;
            aq[mh][ks] = *(const bf16x8*)&q_lds[(row * 16 + (c ^ (row & 7))) * 8];
        }

    float l_j[MH][4] = {};
    f32x4 ov[MH][5] = {};

    int nT = (QR == 64) ? 1 : (SEQ / 64);
    int tBase = (QR == 64) ? qt : 0;

    // prologue: stage K/V tile 0 via global_load_lds
    {
        int key0 = tBase * 64;
#pragma unroll
        for (int i = 0; i < 4; i++) {
            int slot = i * 256 + tid;
            int row = slot >> 4, c = (slot & 15) ^ (row & 7);
            gld16(Kh + (size_t)(key0 + row) * 128 + c * 8, &k_lds[(i * 256 + wave * 64) * 8]);
        }
#pragma unroll
        for (int i = 0; i < 2; i++) {
            int slot = i * 256 + tid;
            int row = slot >> 3, c = (slot & 7) ^ (row & 7);
            gld16(Vh + (size_t)row * SEQ + key0 + c * 8, &v_lds[(i * 256 + wave * 64) * 8]);
        }
        if (tid < 128) {
            int slot = 512 + tid;
            int row = slot >> 3, c = (slot & 7) ^ (row & 7);
            gld16(Vh + (size_t)row * SEQ + key0 + c * 8, &v_lds[(512 + (tid >> 6) * 64) * 8]);
        }
    }
    __syncthreads();

    for (int t = 0; t < nT; t++) {
        bool pf = (t + 1 < nT);
        uint4 kreg[4], vreg[3];
        if (pf) {
            int keyN = (tBase + t + 1) * 64;
#pragma unroll
            for (int i = 0; i < 4; i++) {
                int slot = i * 256 + tid;
                int row = slot >> 4, c = (slot & 15) ^ (row & 7);
                kreg[i] = *(const uint4*)(Kh + (size_t)(keyN + row) * 128 + c * 8);
            }
#pragma unroll
            for (int i = 0; i < 2; i++) {
                int slot = i * 256 + tid;
                int row = slot >> 3, c = (slot & 7) ^ (row & 7);
                vreg[i] = *(const uint4*)(Vh + (size_t)row * SEQ + keyN + c * 8);
            }
            if (tid < 128) {
                int slot = 512 + tid;
                int row = slot >> 3, c = (slot & 7) ^ (row & 7);
                vreg[2] = *(const uint4*)(Vh + (size_t)row * SEQ + keyN + c * 8);
            }
        }

        f32x4 sc[MH][4] = {};
#pragma unroll
        for (int nt = 0; nt < 4; nt++)
#pragma unroll
            for (int ks = 0; ks < 3; ks++) {
                int row = nt * 16 + r15;
                int c = ks * 4 + quad;
                bf16x8 bk = *(const bf16x8*)&k_lds[(row * 16 + (c ^ (row & 7))) * 8];
#pragma unroll
                for (int mh = 0; mh < MH; mh++)
                    sc[mh][nt] = __builtin_amdgcn_mfma_f32_16x16x32_bf16(aq[mh][ks], bk, sc[mh][nt], 0, 0, 0);
            }
#pragma unroll
        for (int mh = 0; mh < MH; mh++)
#pragma unroll
            for (int nt = 0; nt < 4; nt++)
#pragma unroll
                for (int jj = 0; jj < 4; jj++) {
                    float p = __builtin_amdgcn_exp2f(sc[mh][nt][jj] - M2C);
                    l_j[mh][jj] += p;
                    p_lds[(wave * 16 * MH + mh * 16 + quad * 4 + jj) * 72 + nt * 16 + r15] = f2bf(p);
                }
        asm volatile("s_waitcnt lgkmcnt(0)" ::: "memory");
        bf16x8 ap[MH][2];
#pragma unroll
        for (int mh = 0; mh < MH; mh++)
#pragma unroll
            for (int ks = 0; ks < 2; ks++)
                ap[mh][ks] = *(const bf16x8*)&p_lds[(wave * 16 * MH + mh * 16 + r15) * 72 + ks * 32 + quad * 8];
#pragma unroll
        for (int t5 = 0; t5 < 5; t5++)
#pragma unroll
            for (int ks = 0; ks < 2; ks++) {
                int d = t5 * 16 + r15;
                int c = ks * 4 + quad;
                bf16x8 bv = *(const bf16x8*)&v_lds[(d * 8 + (c ^ (d & 7))) * 8];
#pragma unroll
                for (int mh = 0; mh < MH; mh++)
                    ov[mh][t5] = __builtin_amdgcn_mfma_f32_16x16x32_bf16(ap[mh][ks], bv, ov[mh][t5], 0, 0, 0);
            }

        if (pf) {
            __syncthreads();                 // all waves done reading k/v; drains reg loads too
#pragma unroll
            for (int i = 0; i < 4; i++) ((uint4*)k_lds)[i * 256 + tid] = kreg[i];
#pragma unroll
            for (int i = 0; i < 2; i++) ((uint4*)v_lds)[i * 256 + tid] = vreg[i];
            if (tid < 128) ((uint4*)v_lds)[512 + tid] = vreg[2];
            __syncthreads();                 // writes visible before next compute
        }
    }
#pragma unroll
    for (int mh = 0; mh < MH; mh++)
#pragma unroll
        for (int off = 1; off < 16; off <<= 1)
#pragma unroll
            for (int jj = 0; jj < 4; jj++)
                l_j[mh][jj] += __shfl_xor(l_j[mh][jj], off, 64);
    float sink = s_aux[h];
    float se = __builtin_amdgcn_exp2f(sink * LOG2E - M2C);
#pragma unroll
    for (int mh = 0; mh < MH; mh++)
#pragma unroll
        for (int jj = 0; jj < 4; jj++) l_j[mh][jj] = 1.f / (l_j[mh][jj] + se);
#pragma unroll
    for (int mh = 0; mh < MH; mh++)
#pragma unroll
        for (int t5 = 0; t5 < 5; t5++)
#pragma unroll
            for (int jj = 0; jj < 4; jj++) {
                int row = qt * QR + wave * 16 * MH + mh * 16 + quad * 4 + jj;
                int d = t5 * 16 + r15;
                out[(size_t)row * HID + h * 80 + d] = f2bf(ov[mh][t5][jj] * l_j[mh][jj]);
            }
}

__global__ __launch_bounds__(256) void copy4_kernel(const float4* __restrict__ src,
                                                    float4* __restrict__ dst) {
    size_t i = (size_t)blockIdx.x * 256 + threadIdx.x;
    dst[i] = src[i];
}

extern "C" void kernel_launch(void* const* d_in, const int* in_sizes, int n_in,
                              void* d_out, int out_size, void* d_ws, size_t ws_size,
                              hipStream_t stream) {
    const float* x      = (const float*)d_in[0];
    const float* rot    = (const float*)d_in[1];
    const float* s_aux  = (const float*)d_in[2];
    const float* ln1_w  = (const float*)d_in[3];
    const float* ln1_b  = (const float*)d_in[4];
    const float* qkv_w  = (const float*)d_in[5];
    const float* qkv_b  = (const float*)d_in[6];
    const float* proj_w = (const float*)d_in[7];
    const float* proj_b = (const float*)d_in[8];
    const float* ln2_w  = (const float*)d_in[9];
    const float* ln2_b  = (const float*)d_in[10];
    const float* gate_w = (const float*)d_in[11];
    const float* gate_b = (const float*)d_in[12];
    const float* up_w   = (const float*)d_in[13];
    const float* up_b   = (const float*)d_in[14];
    const float* down_w = (const float*)d_in[15];
    const float* down_b = (const float*)d_in[16];

    char* ws = (char*)d_ws;
    size_t off = 0;
    auto alloc = [&](size_t n) -> char* {
        char* p = ws + off; off += (n + 255) & ~(size_t)255; return p;
    };
    u16* wt_qkv  = (u16*)alloc((size_t)4 * 3840 * 1280 * 2);
    u16* wt_proj = (u16*)alloc((size_t)4 * 1280 * 1280 * 2);
    u16* wt_gu   = (u16*)alloc((size_t)4 * 9216 * 1280 * 2);   // interleaved gate/up
    u16* wt_down = (u16*)alloc((size_t)4 * 1280 * 4608 * 2);
    float* h     = (float*)alloc((size_t)3072 * 1280 * 4);
    u16*  xn     = (u16*)alloc((size_t)3072 * 1280 * 2);
    float* gbuf  = (float*)alloc((size_t)3072 * 4608 * 4);
    float* qkvb  = gbuf;  // alias: qkv buffer dead before MLP
    u16*  attnb  = (u16*)alloc((size_t)3072 * 1280 * 2);
    float* ubuf  = (float*)alloc((size_t)3072 * 4608 * 4);
    u16*  mbuf   = (u16*)alloc((size_t)3072 * 4608 * 2);
    u16* Qp  = (u16*)ubuf;
    u16* Kp  = Qp + (size_t)NHEADS * SEQ * 128;
    u16* Vtp = Kp + (size_t)NHEADS * SEQ * 128;

    transpose_pack<<<dim3(120, 40, 4), 256, 0, stream>>>(qkv_w,  wt_qkv,  1280, 3840);
    transpose_pack<<<dim3(40,  40, 4), 256, 0, stream>>>(proj_w, wt_proj, 1280, 1280);
    transpose_pack_gu<<<dim3(144, 40, 4), 256, 0, stream>>>(gate_w, wt_gu, 1280, 4608, 0);
    transpose_pack_gu<<<dim3(144, 40, 4), 256, 0, stream>>>(up_w,   wt_gu, 1280, 4608, 1);
    transpose_pack<<<dim3(40, 144, 4), 256, 0, stream>>>(down_w, wt_down, 4608, 1280);

    copy4_kernel<<<3840, 256, 0, stream>>>((const float4*)x, (float4*)h);

    for (int l = 0; l < 4; l++) {
        ln_kernel<<<3072, 256, 0, stream>>>(h, ln1_w + l * 1280, ln1_b + l * 1280, xn);
        gemm256<0><<<240, 512, 0, stream>>>(xn, wt_qkv + (size_t)l * 3840 * 1280,
                                            qkv_b + l * 3840, nullptr,
                                            qkvb, nullptr, 3840, 1280);
        qkv_pack<<<dim3(48, 16), 256, 0, stream>>>(qkvb, rot, Qp, Kp, Vtp);
        if (l == 3)
            attn_kernel<128><<<dim3(SEQ / 128, 16), 256, 0, stream>>>(Qp, Kp, Vtp, s_aux, attnb);
        else
            attn_kernel<64><<<dim3(SEQ / 64, 16), 256, 0, stream>>>(Qp, Kp, Vtp, s_aux, attnb);
        gemm8<1><<<240, 512, 0, stream>>>(attnb, wt_proj + (size_t)l * 1280 * 1280,
                                          proj_b + l * 1280, h, h, 1280, 1280);
        ln_kernel<<<3072, 256, 0, stream>>>(h, ln2_w + l * 1280, ln2_b + l * 1280, xn);
        gemm256<2><<<576, 512, 0, stream>>>(xn, wt_gu + (size_t)l * 9216 * 1280,
                                            gate_b + l * 4608, up_b + l * 4608,
                                            nullptr, mbuf, 9216, 1280);
        float* outp = (l == 3) ? (float*)d_out : h;
        gemm8<1><<<240, 512, 0, stream>>>(mbuf, wt_down + (size_t)l * 4608 * 1280,
                                          down_b + l * 1280, h, outp, 1280, 4608);
    }
}